// Round 2
// 183.504 us; speedup vs baseline: 1.1607x; 1.1607x over previous
//
#include <hip/hip_runtime.h>

// NeRF render, numerics contract (frozen from r8, PASSED):
//   sdt_i = fmul(sg, fsub(te,ts));  blocked-16 XLA cumsum:
//   s1[g] = within-16 fold of T0 (T0[g] = fold16 of sdt);  upper recursion
//   16384->1024->64->4 sequential folds + combine adds -> C2[16384];
//   C1[j] = (j>>4)? fadd(s1[j], C2[(j>>4)-1]) : s1[j];
//   C_i = g? fadd(fold16_incl(i), C1[g-1]) : fold16_incl(i);
//   excl_i = fsub(C_i, sdt_i);  expo = fsub(excl_i, el[ray]);
//   w = fmul(exp(-expo), fsub(1, exp(-sdt_i))).
// r10 = r9 with two fixes:
//   - k_bottom zeroing bound was n_rays/4 (only 1/4 of out zeroed) -> n_rays
//   - backward-probe loop gets a hard round cap (pure insurance vs device hang)
// Design (r9): wave-autonomous render, zero barriers / zero LDS in k_render:
//   - per-wave head flags via __ballot; el via one __shfl from head lane
//     (head lane's excl IS el - identical arithmetic to old k_heads)
//   - wave-leading partial runs: cooperative backward probe of ri + lane0
//     recomputes C_head with the exact frozen fold
//   - run sums: unsegmented 64-lane shuffle scan + tail difference + atomics
//   - fold16 via 16 ds_swizzle broadcasts, predicated serial adds (same
//     serial left-fold rounding as the LDS loop it replaces)
// 3 dispatches total.

#define TPB 256

__device__ __forceinline__ float sdt_c(float tsv, float tev, float sgv) {
    return __fmul_rn(sgv, __fsub_rn(tev, tsv));
}

// thread = one 16-group: materialize sdt, fold16 -> T0 (LDS), then
// within-16 fold of T0 row -> s1, T1.  Also zeroes out[n_rays][4].
__global__ void k_bottom(const float* __restrict__ ts, const float* __restrict__ te,
                         const float* __restrict__ sg, int S,
                         float* __restrict__ sdt, float* __restrict__ s1,
                         float* __restrict__ T1,
                         float4* __restrict__ out4, int n_rays) {
    __shared__ float st[TPB];
    int t = threadIdx.x;
    int g = blockIdx.x * TPB + t;            // group index < S>>4
    if (g < n_rays) out4[g] = make_float4(0.f, 0.f, 0.f, 0.f);
    const float4* ts4 = (const float4*)ts;
    const float4* te4 = (const float4*)te;
    const float4* sg4 = (const float4*)sg;
    float4* sdt4 = (float4*)sdt;
    float acc = 0.0f;
    #pragma unroll
    for (int k = 0; k < 4; ++k) {
        float4 a = ts4[g * 4 + k], b = te4[g * 4 + k], c = sg4[g * 4 + k];
        float4 xo;
        xo.x = sdt_c(a.x, b.x, c.x);
        xo.y = sdt_c(a.y, b.y, c.y);
        xo.z = sdt_c(a.z, b.z, c.z);
        xo.w = sdt_c(a.w, b.w, c.w);
        acc = __fadd_rn(acc, xo.x);
        acc = __fadd_rn(acc, xo.y);
        acc = __fadd_rn(acc, xo.z);
        acc = __fadd_rn(acc, xo.w);
        sdt4[g * 4 + k] = xo;
    }
    st[t] = acc;                              // T0[g]
    __syncthreads();
    float acc2 = 0.0f;
    int b16 = t & ~15;
    for (int j = 0; j <= (t & 15); ++j) acc2 = __fadd_rn(acc2, st[b16 + j]);
    s1[g] = acc2;
    if ((t & 15) == 15) T1[g >> 4] = acc2;
}

// single block, 1024 threads: scan T1[16384] through levels 2..base -> C2.
__global__ void k_mid(const float* __restrict__ T1, float* __restrict__ C2) {
    __shared__ float T2sh[1024];
    __shared__ float s3sh[1024];   // becomes C3 in place
    __shared__ float s4sh[64];     // becomes C4 in place
    __shared__ float T3sh[64];
    __shared__ float T4sh[4];
    __shared__ float C5sh[4];
    int t = threadIdx.x;
    const float4* T14 = (const float4*)T1;
    float s2l[16];
    float acc = 0.0f;
    #pragma unroll
    for (int k = 0; k < 4; ++k) {
        float4 v = T14[t * 4 + k];
        acc = __fadd_rn(acc, v.x); s2l[k * 4 + 0] = acc;
        acc = __fadd_rn(acc, v.y); s2l[k * 4 + 1] = acc;
        acc = __fadd_rn(acc, v.z); s2l[k * 4 + 2] = acc;
        acc = __fadd_rn(acc, v.w); s2l[k * 4 + 3] = acc;
    }
    T2sh[t] = acc;
    __syncthreads();
    if (t < 64) {                  // level 3
        float a3 = 0.0f;
        for (int j = 0; j < 16; ++j) { a3 = __fadd_rn(a3, T2sh[t * 16 + j]); s3sh[t * 16 + j] = a3; }
        T3sh[t] = a3;
    }
    __syncthreads();
    if (t < 4) {                   // level 4
        float a4 = 0.0f;
        for (int j = 0; j < 16; ++j) { a4 = __fadd_rn(a4, T3sh[t * 16 + j]); s4sh[t * 16 + j] = a4; }
        T4sh[t] = a4;
    }
    __syncthreads();
    if (t == 0) {                  // base fold of 4
        float c = 0.0f;
        for (int r = 0; r < 4; ++r) { c = __fadd_rn(c, T4sh[r]); C5sh[r] = c; }
    }
    __syncthreads();
    if (t < 64) {                  // C4 in place
        int r = t >> 4;
        float v4 = s4sh[t];
        s4sh[t] = r ? __fadd_rn(v4, C5sh[r - 1]) : v4;
    }
    __syncthreads();
    {                              // C3 in place (each thread own index)
        int r = t >> 4;
        float v3 = s3sh[t];
        float c3 = r ? __fadd_rn(v3, s4sh[r - 1]) : v3;
        s3sh[t] = c3;
    }
    __syncthreads();
    float c3m = t ? s3sh[t - 1] : 0.0f;   // C3[t-1]
    float4* C24 = (float4*)C2;
    #pragma unroll
    for (int k = 0; k < 4; ++k) {
        float4 o;
        o.x = t ? __fadd_rn(s2l[k * 4 + 0], c3m) : s2l[k * 4 + 0];
        o.y = t ? __fadd_rn(s2l[k * 4 + 1], c3m) : s2l[k * 4 + 1];
        o.z = t ? __fadd_rn(s2l[k * 4 + 2], c3m) : s2l[k * 4 + 2];
        o.w = t ? __fadd_rn(s2l[k * 4 + 3], c3m) : s2l[k * 4 + 3];
        C24[t * 4 + k] = o;
    }
}

// wave-autonomous render: coalesced reads, zero barriers, zero LDS.
// Head flags via ballot, el via shfl from head lane (or backward probe for
// wave-leading runs), run sums via wave shuffle scan + tail atomics.
__global__ void k_render(const int* __restrict__ ri, const float* __restrict__ sdt,
                         const float* __restrict__ s1, const float* __restrict__ C2,
                         const float* __restrict__ hdr,
                         int S, float* __restrict__ out) {
    int t = threadIdx.x & 63;                 // lane
    int i = blockIdx.x * TPB + threadIdx.x;   // sample
    int wb = i - t;                            // wave-base sample index
    bool valid = i < S;
    float x = valid ? sdt[i] : 0.0f;
    int r = valid ? ri[i] : -1;

    // ---- head flags (all lanes straight-line up to the ballot)
    int pr = __shfl_up(r, 1, 64);
    if (t == 0) pr = (i == 0) ? (r ^ 1) : ri[i - 1];
    bool f = (pr != r);
    unsigned long long mask = __ballot(f);

    // ---- fold16: exact serial left-fold of the 16-group via ds_swizzle
    // broadcasts (lane' = (lane & 0x10) | J within each 32-half).
    int l = t & 15;
    float acc = 0.0f;
#define FSTEP(J) { float vj = __int_as_float(__builtin_amdgcn_ds_swizzle( \
                       __float_as_int(x), (((J) << 5) | 0x10)));          \
                   if ((J) <= l) acc = __fadd_rn(acc, vj); }
    FSTEP(0)  FSTEP(1)  FSTEP(2)  FSTEP(3)
    FSTEP(4)  FSTEP(5)  FSTEP(6)  FSTEP(7)
    FSTEP(8)  FSTEP(9)  FSTEP(10) FSTEP(11)
    FSTEP(12) FSTEP(13) FSTEP(14) FSTEP(15)
#undef FSTEP

    int g = i >> 4;
    float Ci = acc;
    if (g) {
        int j = g - 1;
        float cj = (j >> 4) ? __fadd_rn(s1[j], C2[(j >> 4) - 1]) : s1[j];
        Ci = __fadd_rn(acc, cj);
    }
    float excl = __fsub_rn(Ci, x);

    // ---- el for the wave-leading run (head in an earlier wave)
    unsigned long long bits_le = mask & (~0ull >> (63 - t));
    float el_lead = 0.0f;
    if (!(mask & 1ull)) {                     // wave-uniform branch
        int r0 = __shfl(r, 0, 64);
        int h0 = 0;
        // cap is pure insurance: idx<0 lanes force a mismatch, so the loop
        // terminates logically within (wb/64)+1 rounds.
        for (int round = 0; round < 65536; ++round) {
            int idx = wb - 1 - t - 64 * round;
            int rv = (idx >= 0) ? ri[idx] : (r0 ^ 1);
            unsigned long long mm = __ballot(rv != r0);
            if (mm) {
                int lm = __ffsll((unsigned long long)mm) - 1; // lowest lane = largest idx
                h0 = wb - 64 * round - lm;                    // mismatch idx + 1
                break;
            }
        }
        float elv = 0.0f;
        if (t == 0) {                         // recompute C_head per frozen contract
            const float4* s4 = (const float4*)sdt;
            int gh = h0 >> 4, lh = h0 & 15;
            float4 q0 = s4[gh * 4 + 0], q1 = s4[gh * 4 + 1];
            float4 q2 = s4[gh * 4 + 2], q3 = s4[gh * 4 + 3];
            float vv[16] = { q0.x, q0.y, q0.z, q0.w, q1.x, q1.y, q1.z, q1.w,
                             q2.x, q2.y, q2.z, q2.w, q3.x, q3.y, q3.z, q3.w };
            float a2 = 0.0f, xl = 0.0f;
            #pragma unroll
            for (int j2 = 0; j2 < 16; ++j2) {
                if (j2 <= lh) { a2 = __fadd_rn(a2, vv[j2]); xl = vv[j2]; }
            }
            float Ch = a2;
            if (gh) {
                int j3 = gh - 1;
                float cj = (j3 >> 4) ? __fadd_rn(s1[j3], C2[(j3 >> 4) - 1]) : s1[j3];
                Ch = __fadd_rn(a2, cj);
            }
            elv = __fsub_rn(Ch, xl);
        }
        el_lead = __shfl(elv, 0, 64);
    }

    // ---- el via shfl from head lane (head lane's excl == el, same math as old k_heads)
    int h = bits_le ? (63 - __clzll((long long)bits_le)) : 0;
    int esrc = bits_le ? h : t;
    float elh = __shfl(excl, esrc, 64);       // all lanes participate
    float el = bits_le ? elh : el_lead;

    // ---- weights
    float w = 0.0f, hr = 0.0f, hg = 0.0f, hb = 0.0f;
    if (valid) {
        float expo  = __fsub_rn(excl, el);
        float trans = __expf(-expo);
        float alpha = __fsub_rn(1.0f, __expf(-x));
        w  = __fmul_rn(trans, alpha);
        hr = hdr[3 * i + 0]; hg = hdr[3 * i + 1]; hb = hdr[3 * i + 2];
    }
    float4 v = make_float4(w, __fmul_rn(w, hr), __fmul_rn(w, hg), __fmul_rn(w, hb));

    // ---- unsegmented inclusive wave scan (Hillis-Steele, shuffles only)
    float4 sc = v;
    #pragma unroll
    for (int s = 1; s < 64; s <<= 1) {
        float4 p;
        p.x = __shfl_up(sc.x, s, 64);
        p.y = __shfl_up(sc.y, s, 64);
        p.z = __shfl_up(sc.z, s, 64);
        p.w = __shfl_up(sc.w, s, 64);
        if (t >= s) { sc.x += p.x; sc.y += p.y; sc.z += p.z; sc.w += p.w; }
    }

    // ---- run base = scan value just before my run's first in-wave lane
    int bsrc = (h > 0) ? (h - 1) : t;
    float4 bs;
    bs.x = __shfl(sc.x, bsrc, 64);
    bs.y = __shfl(sc.y, bsrc, 64);
    bs.z = __shfl(sc.z, bsrc, 64);
    bs.w = __shfl(sc.w, bsrc, 64);
    if (h == 0) { bs.x = 0.f; bs.y = 0.f; bs.z = 0.f; bs.w = 0.f; }

    // ---- tails: one atomic partial-sum per (wave, run) piece
    bool nf = (t < 63) ? (((mask >> (t + 1)) & 1ull) != 0ull) : true;
    if (valid && nf && r >= 0) {
        float* o = out + 4 * r;
        atomicAdd(o + 0, sc.x - bs.x);
        atomicAdd(o + 1, sc.y - bs.y);
        atomicAdd(o + 2, sc.z - bs.z);
        atomicAdd(o + 3, sc.w - bs.w);
    }
}

extern "C" void kernel_launch(void* const* d_in, const int* in_sizes, int n_in,
                              void* d_out, int out_size, void* d_ws, size_t ws_size,
                              hipStream_t stream) {
    const float* ts  = (const float*)d_in[0];
    const float* te  = (const float*)d_in[1];
    const float* sg  = (const float*)d_in[2];
    const float* hdr = (const float*)d_in[3];
    const int*   ri  = (const int*)d_in[4];
    const int S      = in_sizes[0];          // 4194304 = 2^22
    const int n_rays = out_size / 4;
    const int N1 = S >> 4;                   // 262144
    const int N2 = N1 >> 4;                  // 16384

    char* w = (char*)d_ws;
    auto alloc = [&](size_t bytes) { char* p = w; w += (bytes + 255) & ~255ULL; return p; };
    float* sdt = (float*)alloc((size_t)S * 4);
    float* s1  = (float*)alloc((size_t)N1 * 4);
    float* T1  = (float*)alloc((size_t)N2 * 4);
    float* C2  = (float*)alloc((size_t)N2 * 4);

    k_bottom<<<dim3(N1 / TPB), dim3(TPB), 0, stream>>>(ts, te, sg, S, sdt, s1, T1,
                                                       (float4*)d_out, n_rays);
    k_mid   <<<dim3(1), dim3(1024), 0, stream>>>(T1, C2);
    k_render<<<dim3((S + TPB - 1) / TPB), dim3(TPB), 0, stream>>>(ri, sdt, s1, C2, hdr, S, (float*)d_out);
}

// Round 3
// 178.005 us; speedup vs baseline: 1.1966x; 1.0309x over previous
//
#include <hip/hip_runtime.h>

// NeRF render, numerics contract (frozen from r8, PASSED):
//   sdt_i = fmul(sg, fsub(te,ts));  blocked-16 XLA cumsum:
//   s1[g] = within-16 fold of T0 (T0[g] = fold16 of sdt);  upper recursion
//   16384->1024->64->4 sequential folds + combine adds -> C2[16384];
//   C1[j] = (j>>4)? fadd(s1[j], C2[(j>>4)-1]) : s1[j];
//   C_i = g? fadd(fold16_incl(i), C1[g-1]) : fold16_incl(i);
//   excl_i = fsub(C_i, sdt_i);  expo = fsub(excl_i, el[ray]);
//   w = fmul(exp(-expo), fsub(1, exp(-sdt_i))).
// r11: DS-pipe -> VALU-pipe. r10's k_render was DS-pipe-bound (~50 LDS-pipe
// ops/thread: 16 ds_swizzle fold16 + ~25 bpermute shfl scan; VALUBusy 47%,
// HBM 14% -> nothing else saturated). All row-structured cross-lane moves
// now use GFX9 DPP (VALU pipe, no LDS traffic):
//   - fold16: update_dpp(old=0, row_shr:J) gives v_{l-J} or exact 0.0;
//     fadd(acc, 0.0) is a bit-exact no-op -> serial left-fold order preserved.
//   - wave scan: shr1/2/4/8 + bcast15 (rows 1,3) + bcast31 (rows 2,3).
//   - head flags: second coalesced load ri[i-1] (VMEM) instead of shfl_up.
//   - el_lead broadcast: readfirstlane (SALU).
// Remaining DS ops: 5 variable-index shfls (el from head lane, float4 base).
// k_bottom: same DPP fold16 replaces LDS+barrier round trip.
// 3 dispatches.

#define TPB 256

// update_dpp with old=0: masked/invalid lanes yield exactly 0.0f.
#define DPP0(SRC, CTRL, RMASK, BC) __int_as_float(__builtin_amdgcn_update_dpp( \
        0, __float_as_int(SRC), (CTRL), (RMASK), 0xf, (BC)))

// serial left-fold prefix within each 16-lane row, exact contract order:
// acc = fadd(...fadd(fadd(0, v_b), v_{b+1})..., v_l); leading fadd(acc,0)
// terms are bit-exact no-ops.
__device__ __forceinline__ float fold16_dpp(float x) {
    float a = 0.0f;
    a = __fadd_rn(a, DPP0(x, 0x110 | 15, 0xf, true));
    a = __fadd_rn(a, DPP0(x, 0x110 | 14, 0xf, true));
    a = __fadd_rn(a, DPP0(x, 0x110 | 13, 0xf, true));
    a = __fadd_rn(a, DPP0(x, 0x110 | 12, 0xf, true));
    a = __fadd_rn(a, DPP0(x, 0x110 | 11, 0xf, true));
    a = __fadd_rn(a, DPP0(x, 0x110 | 10, 0xf, true));
    a = __fadd_rn(a, DPP0(x, 0x110 |  9, 0xf, true));
    a = __fadd_rn(a, DPP0(x, 0x110 |  8, 0xf, true));
    a = __fadd_rn(a, DPP0(x, 0x110 |  7, 0xf, true));
    a = __fadd_rn(a, DPP0(x, 0x110 |  6, 0xf, true));
    a = __fadd_rn(a, DPP0(x, 0x110 |  5, 0xf, true));
    a = __fadd_rn(a, DPP0(x, 0x110 |  4, 0xf, true));
    a = __fadd_rn(a, DPP0(x, 0x110 |  3, 0xf, true));
    a = __fadd_rn(a, DPP0(x, 0x110 |  2, 0xf, true));
    a = __fadd_rn(a, DPP0(x, 0x110 |  1, 0xf, true));
    a = __fadd_rn(a, x);
    return a;
}

// inclusive 64-lane scan (rounding-free path: segment sums only)
__device__ __forceinline__ float wscan(float v) {
    v = __fadd_rn(v, DPP0(v, 0x111, 0xf, true));   // row_shr:1
    v = __fadd_rn(v, DPP0(v, 0x112, 0xf, true));   // row_shr:2
    v = __fadd_rn(v, DPP0(v, 0x114, 0xf, true));   // row_shr:4
    v = __fadd_rn(v, DPP0(v, 0x118, 0xf, true));   // row_shr:8
    v = __fadd_rn(v, DPP0(v, 0x142, 0xa, false));  // row_bcast15 -> rows 1,3
    v = __fadd_rn(v, DPP0(v, 0x143, 0xc, false));  // row_bcast31 -> rows 2,3
    return v;
}

__device__ __forceinline__ float sdt_c(float tsv, float tev, float sgv) {
    return __fmul_rn(sgv, __fsub_rn(tev, tsv));
}

// thread = one 16-group: materialize sdt, fold16 -> T0 (reg), DPP row fold
// of T0 -> s1, T1.  Also zeroes out[n_rays][4].  No LDS, no barrier.
__global__ void k_bottom(const float* __restrict__ ts, const float* __restrict__ te,
                         const float* __restrict__ sg, int S,
                         float* __restrict__ sdt, float* __restrict__ s1,
                         float* __restrict__ T1,
                         float4* __restrict__ out4, int n_rays) {
    int t = threadIdx.x;
    int g = blockIdx.x * TPB + t;            // group index < S>>4
    if (g < n_rays) out4[g] = make_float4(0.f, 0.f, 0.f, 0.f);
    const float4* ts4 = (const float4*)ts;
    const float4* te4 = (const float4*)te;
    const float4* sg4 = (const float4*)sg;
    float4* sdt4 = (float4*)sdt;
    float acc = 0.0f;
    #pragma unroll
    for (int k = 0; k < 4; ++k) {
        float4 a = ts4[g * 4 + k], b = te4[g * 4 + k], c = sg4[g * 4 + k];
        float4 xo;
        xo.x = sdt_c(a.x, b.x, c.x);
        xo.y = sdt_c(a.y, b.y, c.y);
        xo.z = sdt_c(a.z, b.z, c.z);
        xo.w = sdt_c(a.w, b.w, c.w);
        acc = __fadd_rn(acc, xo.x);
        acc = __fadd_rn(acc, xo.y);
        acc = __fadd_rn(acc, xo.z);
        acc = __fadd_rn(acc, xo.w);
        sdt4[g * 4 + k] = xo;
    }
    // within-16(-lane-row) serial fold of T0 -> s1 (exact contract order)
    float acc2 = fold16_dpp(acc);
    s1[g] = acc2;
    if ((t & 15) == 15) T1[g >> 4] = acc2;
}

// single block, 1024 threads: scan T1[16384] through levels 2..base -> C2.
__global__ void k_mid(const float* __restrict__ T1, float* __restrict__ C2) {
    __shared__ float T2sh[1024];
    __shared__ float s3sh[1024];   // becomes C3 in place
    __shared__ float s4sh[64];     // becomes C4 in place
    __shared__ float T3sh[64];
    __shared__ float T4sh[4];
    __shared__ float C5sh[4];
    int t = threadIdx.x;
    const float4* T14 = (const float4*)T1;
    float s2l[16];
    float acc = 0.0f;
    #pragma unroll
    for (int k = 0; k < 4; ++k) {
        float4 v = T14[t * 4 + k];
        acc = __fadd_rn(acc, v.x); s2l[k * 4 + 0] = acc;
        acc = __fadd_rn(acc, v.y); s2l[k * 4 + 1] = acc;
        acc = __fadd_rn(acc, v.z); s2l[k * 4 + 2] = acc;
        acc = __fadd_rn(acc, v.w); s2l[k * 4 + 3] = acc;
    }
    T2sh[t] = acc;
    __syncthreads();
    if (t < 64) {                  // level 3
        float a3 = 0.0f;
        for (int j = 0; j < 16; ++j) { a3 = __fadd_rn(a3, T2sh[t * 16 + j]); s3sh[t * 16 + j] = a3; }
        T3sh[t] = a3;
    }
    __syncthreads();
    if (t < 4) {                   // level 4
        float a4 = 0.0f;
        for (int j = 0; j < 16; ++j) { a4 = __fadd_rn(a4, T3sh[t * 16 + j]); s4sh[t * 16 + j] = a4; }
        T4sh[t] = a4;
    }
    __syncthreads();
    if (t == 0) {                  // base fold of 4
        float c = 0.0f;
        for (int r = 0; r < 4; ++r) { c = __fadd_rn(c, T4sh[r]); C5sh[r] = c; }
    }
    __syncthreads();
    if (t < 64) {                  // C4 in place
        int r = t >> 4;
        float v4 = s4sh[t];
        s4sh[t] = r ? __fadd_rn(v4, C5sh[r - 1]) : v4;
    }
    __syncthreads();
    {                              // C3 in place (each thread own index)
        int r = t >> 4;
        float v3 = s3sh[t];
        float c3 = r ? __fadd_rn(v3, s4sh[r - 1]) : v3;
        s3sh[t] = c3;
    }
    __syncthreads();
    float c3m = t ? s3sh[t - 1] : 0.0f;   // C3[t-1]
    float4* C24 = (float4*)C2;
    #pragma unroll
    for (int k = 0; k < 4; ++k) {
        float4 o;
        o.x = t ? __fadd_rn(s2l[k * 4 + 0], c3m) : s2l[k * 4 + 0];
        o.y = t ? __fadd_rn(s2l[k * 4 + 1], c3m) : s2l[k * 4 + 1];
        o.z = t ? __fadd_rn(s2l[k * 4 + 2], c3m) : s2l[k * 4 + 2];
        o.w = t ? __fadd_rn(s2l[k * 4 + 3], c3m) : s2l[k * 4 + 3];
        C24[t * 4 + k] = o;
    }
}

// wave-autonomous render: coalesced reads, zero barriers, zero LDS arrays,
// cross-lane via DPP (VALU pipe); only 5 variable-index shfls remain.
__global__ void k_render(const int* __restrict__ ri, const float* __restrict__ sdt,
                         const float* __restrict__ s1, const float* __restrict__ C2,
                         const float* __restrict__ hdr,
                         int S, float* __restrict__ out) {
    int t = threadIdx.x & 63;                 // lane
    int i = blockIdx.x * TPB + threadIdx.x;   // sample
    int wb = i - t;                            // wave-base sample index
    bool valid = i < S;
    float x = valid ? sdt[i] : 0.0f;
    int r  = valid ? ri[i] : (-1 - t);
    int pr = valid ? ((i == 0) ? (r ^ 1) : ri[i - 1]) : -1000;

    bool f = (pr != r);
    unsigned long long mask = __ballot(f);

    // ---- fold16 (exact serial left-fold order, DPP)
    float acc = fold16_dpp(x);

    int g = i >> 4;
    float Ci = acc;
    if (g) {
        int j = g - 1;
        float cj = (j >> 4) ? __fadd_rn(s1[j], C2[(j >> 4) - 1]) : s1[j];
        Ci = __fadd_rn(acc, cj);
    }
    float excl = __fsub_rn(Ci, x);

    // ---- el for the wave-leading run (head in an earlier wave)
    unsigned long long bits_le = mask & (~0ull >> (63 - t));
    float el_lead = 0.0f;
    if (!(mask & 1ull)) {                     // wave-uniform branch
        int r0 = __builtin_amdgcn_readfirstlane(r);
        int h0 = 0;
        // cap is insurance: idx<0 lanes force a mismatch, loop terminates
        // logically within (wb/64)+1 rounds.
        for (int round = 0; round < 65536; ++round) {
            int idx = wb - 1 - t - 64 * round;
            int rv = (idx >= 0) ? ri[idx] : (r0 ^ 1);
            unsigned long long mm = __ballot(rv != r0);
            if (mm) {
                int lm = __ffsll((unsigned long long)mm) - 1; // lowest lane = largest idx
                h0 = wb - 64 * round - lm;                    // mismatch idx + 1
                break;
            }
        }
        float elv = 0.0f;
        if (t == 0) {                         // recompute C_head per frozen contract
            const float4* s4 = (const float4*)sdt;
            int gh = h0 >> 4, lh = h0 & 15;
            float4 q0 = s4[gh * 4 + 0], q1 = s4[gh * 4 + 1];
            float4 q2 = s4[gh * 4 + 2], q3 = s4[gh * 4 + 3];
            float vv[16] = { q0.x, q0.y, q0.z, q0.w, q1.x, q1.y, q1.z, q1.w,
                             q2.x, q2.y, q2.z, q2.w, q3.x, q3.y, q3.z, q3.w };
            float a2 = 0.0f, xl = 0.0f;
            #pragma unroll
            for (int j2 = 0; j2 < 16; ++j2) {
                if (j2 <= lh) { a2 = __fadd_rn(a2, vv[j2]); xl = vv[j2]; }
            }
            float Ch = a2;
            if (gh) {
                int j3 = gh - 1;
                float cj = (j3 >> 4) ? __fadd_rn(s1[j3], C2[(j3 >> 4) - 1]) : s1[j3];
                Ch = __fadd_rn(a2, cj);
            }
            elv = __fsub_rn(Ch, xl);
        }
        el_lead = __int_as_float(__builtin_amdgcn_readfirstlane(__float_as_int(elv)));
    }

    // ---- el via shfl from head lane (head lane's excl == el)
    int h = bits_le ? (63 - __clzll((long long)bits_le)) : 0;
    int esrc = bits_le ? h : t;
    float elh = __shfl(excl, esrc, 64);       // all lanes participate
    float el = bits_le ? elh : el_lead;

    // ---- weights
    float w = 0.0f, hr = 0.0f, hg = 0.0f, hb = 0.0f;
    if (valid) {
        float expo  = __fsub_rn(excl, el);
        float trans = __expf(-expo);
        float alpha = __fsub_rn(1.0f, __expf(-x));
        w  = __fmul_rn(trans, alpha);
        hr = hdr[3 * i + 0]; hg = hdr[3 * i + 1]; hb = hdr[3 * i + 2];
    }

    // ---- unsegmented inclusive wave scan (DPP, VALU pipe)
    float4 sc;
    sc.x = wscan(w);
    sc.y = wscan(__fmul_rn(w, hr));
    sc.z = wscan(__fmul_rn(w, hg));
    sc.w = wscan(__fmul_rn(w, hb));

    // ---- run base = scan value just before my run's first in-wave lane
    int bsrc = (h > 0) ? (h - 1) : t;
    float4 bs;
    bs.x = __shfl(sc.x, bsrc, 64);
    bs.y = __shfl(sc.y, bsrc, 64);
    bs.z = __shfl(sc.z, bsrc, 64);
    bs.w = __shfl(sc.w, bsrc, 64);
    if (h == 0) { bs.x = 0.f; bs.y = 0.f; bs.z = 0.f; bs.w = 0.f; }

    // ---- tails: one atomic partial-sum per (wave, run) piece
    bool nf = (t < 63) ? (((mask >> (t + 1)) & 1ull) != 0ull) : true;
    if (valid && nf && r >= 0) {
        float* o = out + 4 * r;
        atomicAdd(o + 0, sc.x - bs.x);
        atomicAdd(o + 1, sc.y - bs.y);
        atomicAdd(o + 2, sc.z - bs.z);
        atomicAdd(o + 3, sc.w - bs.w);
    }
}

extern "C" void kernel_launch(void* const* d_in, const int* in_sizes, int n_in,
                              void* d_out, int out_size, void* d_ws, size_t ws_size,
                              hipStream_t stream) {
    const float* ts  = (const float*)d_in[0];
    const float* te  = (const float*)d_in[1];
    const float* sg  = (const float*)d_in[2];
    const float* hdr = (const float*)d_in[3];
    const int*   ri  = (const int*)d_in[4];
    const int S      = in_sizes[0];          // 4194304 = 2^22
    const int n_rays = out_size / 4;
    const int N1 = S >> 4;                   // 262144
    const int N2 = N1 >> 4;                  // 16384

    char* w = (char*)d_ws;
    auto alloc = [&](size_t bytes) { char* p = w; w += (bytes + 255) & ~255ULL; return p; };
    float* sdt = (float*)alloc((size_t)S * 4);
    float* s1  = (float*)alloc((size_t)N1 * 4);
    float* T1  = (float*)alloc((size_t)N2 * 4);
    float* C2  = (float*)alloc((size_t)N2 * 4);

    k_bottom<<<dim3(N1 / TPB), dim3(TPB), 0, stream>>>(ts, te, sg, S, sdt, s1, T1,
                                                       (float4*)d_out, n_rays);
    k_mid   <<<dim3(1), dim3(1024), 0, stream>>>(T1, C2);
    k_render<<<dim3((S + TPB - 1) / TPB), dim3(TPB), 0, stream>>>(ri, sdt, s1, C2, hdr, S, (float*)d_out);
}

// Round 5
// 177.027 us; speedup vs baseline: 1.2032x; 1.0055x over previous
//
#include <hip/hip_runtime.h>

// NeRF render, numerics contract (frozen from r8, PASSED):
//   sdt_i = fmul(sg, fsub(te,ts));  blocked-16 XLA cumsum:
//   s1[g] = within-16 fold of T0 (T0[g] = fold16 of sdt);  upper recursion
//   16384->1024->64->4 sequential folds + combine adds -> C2[16384];
//   C1[j] = (j>>4)? fadd(s1[j], C2[(j>>4)-1]) : s1[j];
//   C_i = g? fadd(fold16_incl(i), C1[g-1]) : fold16_incl(i);
//   excl_i = fsub(C_i, sdt_i);  expo = fsub(excl_i, el[ray]);
//   w = fmul(exp(-expo), fsub(1, exp(-sdt_i))).
// r13: r4's cooperative launch silently no-ops under the harness's graph
// capture (out stayed memset-zero -> absmax == max|ref|). Revert to the r3
// 3-dispatch structure (PASSED) and change ONLY k_bottom internals:
// fully-coalesced float4 loads (r3 had 64B lane stride -> 64 cachelines per
// global_load_dwordx4), LDS-staged transpose (stride-17 pad: conflict-free
// reads, worst 2-way writes = free), per-thread serial fold from LDS.
// Serial left-fold chains are op-for-op identical; only plumbing changed.
// k_mid / k_render: byte-identical to r3 (PASSED).

#define TPB 256
#define LDSF (256 * 17)      // padded tile: 256 groups x 16 + pad

// update_dpp with old=0: masked/invalid lanes yield exactly 0.0f.
#define DPP0(SRC, CTRL, RMASK, BC) __int_as_float(__builtin_amdgcn_update_dpp( \
        0, __float_as_int(SRC), (CTRL), (RMASK), 0xf, (BC)))

// serial left-fold prefix within each 16-lane row, exact contract order:
// leading fadd(acc, 0.0) terms are bit-exact no-ops.
__device__ __forceinline__ float fold16_dpp(float x) {
    float a = 0.0f;
    a = __fadd_rn(a, DPP0(x, 0x110 | 15, 0xf, true));
    a = __fadd_rn(a, DPP0(x, 0x110 | 14, 0xf, true));
    a = __fadd_rn(a, DPP0(x, 0x110 | 13, 0xf, true));
    a = __fadd_rn(a, DPP0(x, 0x110 | 12, 0xf, true));
    a = __fadd_rn(a, DPP0(x, 0x110 | 11, 0xf, true));
    a = __fadd_rn(a, DPP0(x, 0x110 | 10, 0xf, true));
    a = __fadd_rn(a, DPP0(x, 0x110 |  9, 0xf, true));
    a = __fadd_rn(a, DPP0(x, 0x110 |  8, 0xf, true));
    a = __fadd_rn(a, DPP0(x, 0x110 |  7, 0xf, true));
    a = __fadd_rn(a, DPP0(x, 0x110 |  6, 0xf, true));
    a = __fadd_rn(a, DPP0(x, 0x110 |  5, 0xf, true));
    a = __fadd_rn(a, DPP0(x, 0x110 |  4, 0xf, true));
    a = __fadd_rn(a, DPP0(x, 0x110 |  3, 0xf, true));
    a = __fadd_rn(a, DPP0(x, 0x110 |  2, 0xf, true));
    a = __fadd_rn(a, DPP0(x, 0x110 |  1, 0xf, true));
    a = __fadd_rn(a, x);
    return a;
}

// inclusive 64-lane scan (segment sums only; rounding-free path)
__device__ __forceinline__ float wscan(float v) {
    v = __fadd_rn(v, DPP0(v, 0x111, 0xf, true));   // row_shr:1
    v = __fadd_rn(v, DPP0(v, 0x112, 0xf, true));   // row_shr:2
    v = __fadd_rn(v, DPP0(v, 0x114, 0xf, true));   // row_shr:4
    v = __fadd_rn(v, DPP0(v, 0x118, 0xf, true));   // row_shr:8
    v = __fadd_rn(v, DPP0(v, 0x142, 0xa, false));  // row_bcast15 -> rows 1,3
    v = __fadd_rn(v, DPP0(v, 0x143, 0xc, false));  // row_bcast31 -> rows 2,3
    return v;
}

__device__ __forceinline__ float sdt_c(float tsv, float tev, float sgv) {
    return __fmul_rn(sgv, __fsub_rn(tev, tsv));
}

// block = one 4096-float tile: coalesced loads of ts/te/sg, sdt computed and
// written coalesced, staged into padded LDS; after barrier thread t serially
// folds group (tile*256+t) from LDS (exact contract chain), fold16_dpp -> s1.
__global__ void k_bottom(const float* __restrict__ ts, const float* __restrict__ te,
                         const float* __restrict__ sg, int S,
                         float* __restrict__ sdt, float* __restrict__ s1,
                         float* __restrict__ T1,
                         float4* __restrict__ out4, int n_rays) {
    __shared__ float lds[LDSF];
    int t = threadIdx.x;
    int tile = blockIdx.x;                    // grid = N1/TPB = 1024 tiles
    int gid = tile * TPB + t;
    if (gid < n_rays) out4[gid] = make_float4(0.f, 0.f, 0.f, 0.f);
    const float4* ts4 = (const float4*)ts;
    const float4* te4 = (const float4*)te;
    const float4* sg4 = (const float4*)sg;
    float4* sdt4 = (float4*)sdt;
    #pragma unroll
    for (int k = 0; k < 4; ++k) {
        int idx4 = tile * 1024 + k * 256 + t;  // lane-contiguous float4
        float4 a = ts4[idx4], b = te4[idx4], c = sg4[idx4];
        float4 xo;
        xo.x = sdt_c(a.x, b.x, c.x);
        xo.y = sdt_c(a.y, b.y, c.y);
        xo.z = sdt_c(a.z, b.z, c.z);
        xo.w = sdt_c(a.w, b.w, c.w);
        sdt4[idx4] = xo;                       // coalesced write
        int fl = (k * 256 + t) << 2;           // float idx within tile
        int g0 = fl >> 4, j0 = fl & 15;
        float* p = &lds[g0 * 17 + j0];
        p[0] = xo.x; p[1] = xo.y; p[2] = xo.z; p[3] = xo.w;
    }
    __syncthreads();
    // serial fold of this thread's 16-group (exact contract chain)
    float acc = 0.0f;
    #pragma unroll
    for (int j = 0; j < 16; ++j) acc = __fadd_rn(acc, lds[t * 17 + j]);
    float acc2 = fold16_dpp(acc);              // within-16 row fold -> s1
    int g = tile * 256 + t;
    s1[g] = acc2;
    if ((t & 15) == 15) T1[g >> 4] = acc2;
}

// single block, 1024 threads: scan T1[16384] through levels 2..base -> C2.
__global__ void k_mid(const float* __restrict__ T1, float* __restrict__ C2) {
    __shared__ float T2sh[1024];
    __shared__ float s3sh[1024];   // becomes C3 in place
    __shared__ float s4sh[64];     // becomes C4 in place
    __shared__ float T3sh[64];
    __shared__ float T4sh[4];
    __shared__ float C5sh[4];
    int t = threadIdx.x;
    const float4* T14 = (const float4*)T1;
    float s2l[16];
    float acc = 0.0f;
    #pragma unroll
    for (int k = 0; k < 4; ++k) {
        float4 v = T14[t * 4 + k];
        acc = __fadd_rn(acc, v.x); s2l[k * 4 + 0] = acc;
        acc = __fadd_rn(acc, v.y); s2l[k * 4 + 1] = acc;
        acc = __fadd_rn(acc, v.z); s2l[k * 4 + 2] = acc;
        acc = __fadd_rn(acc, v.w); s2l[k * 4 + 3] = acc;
    }
    T2sh[t] = acc;
    __syncthreads();
    if (t < 64) {                  // level 3
        float a3 = 0.0f;
        for (int j = 0; j < 16; ++j) { a3 = __fadd_rn(a3, T2sh[t * 16 + j]); s3sh[t * 16 + j] = a3; }
        T3sh[t] = a3;
    }
    __syncthreads();
    if (t < 4) {                   // level 4
        float a4 = 0.0f;
        for (int j = 0; j < 16; ++j) { a4 = __fadd_rn(a4, T3sh[t * 16 + j]); s4sh[t * 16 + j] = a4; }
        T4sh[t] = a4;
    }
    __syncthreads();
    if (t == 0) {                  // base fold of 4
        float c = 0.0f;
        for (int r = 0; r < 4; ++r) { c = __fadd_rn(c, T4sh[r]); C5sh[r] = c; }
    }
    __syncthreads();
    if (t < 64) {                  // C4 in place
        int r = t >> 4;
        float v4 = s4sh[t];
        s4sh[t] = r ? __fadd_rn(v4, C5sh[r - 1]) : v4;
    }
    __syncthreads();
    {                              // C3 in place (each thread own index)
        int r = t >> 4;
        float v3 = s3sh[t];
        float c3 = r ? __fadd_rn(v3, s4sh[r - 1]) : v3;
        s3sh[t] = c3;
    }
    __syncthreads();
    float c3m = t ? s3sh[t - 1] : 0.0f;   // C3[t-1]
    float4* C24 = (float4*)C2;
    #pragma unroll
    for (int k = 0; k < 4; ++k) {
        float4 o;
        o.x = t ? __fadd_rn(s2l[k * 4 + 0], c3m) : s2l[k * 4 + 0];
        o.y = t ? __fadd_rn(s2l[k * 4 + 1], c3m) : s2l[k * 4 + 1];
        o.z = t ? __fadd_rn(s2l[k * 4 + 2], c3m) : s2l[k * 4 + 2];
        o.w = t ? __fadd_rn(s2l[k * 4 + 3], c3m) : s2l[k * 4 + 3];
        C24[t * 4 + k] = o;
    }
}

// wave-autonomous render: coalesced reads, zero barriers, zero LDS arrays,
// cross-lane via DPP (VALU pipe); only 5 variable-index shfls remain.
__global__ void k_render(const int* __restrict__ ri, const float* __restrict__ sdt,
                         const float* __restrict__ s1, const float* __restrict__ C2,
                         const float* __restrict__ hdr,
                         int S, float* __restrict__ out) {
    int t = threadIdx.x & 63;                 // lane
    int i = blockIdx.x * TPB + threadIdx.x;   // sample
    int wb = i - t;                            // wave-base sample index
    bool valid = i < S;
    float x = valid ? sdt[i] : 0.0f;
    int r  = valid ? ri[i] : (-1 - t);
    int pr = valid ? ((i == 0) ? (r ^ 1) : ri[i - 1]) : -1000;

    bool f = (pr != r);
    unsigned long long mask = __ballot(f);

    // ---- fold16 (exact serial left-fold order, DPP)
    float acc = fold16_dpp(x);

    int g = i >> 4;
    float Ci = acc;
    if (g) {
        int j = g - 1;
        float cj = (j >> 4) ? __fadd_rn(s1[j], C2[(j >> 4) - 1]) : s1[j];
        Ci = __fadd_rn(acc, cj);
    }
    float excl = __fsub_rn(Ci, x);

    // ---- el for the wave-leading run (head in an earlier wave)
    unsigned long long bits_le = mask & (~0ull >> (63 - t));
    float el_lead = 0.0f;
    if (!(mask & 1ull)) {                     // wave-uniform branch
        int r0 = __builtin_amdgcn_readfirstlane(r);
        int h0 = 0;
        // cap is insurance: idx<0 lanes force a mismatch, loop terminates
        // logically within (wb/64)+1 rounds.
        for (int round = 0; round < 65536; ++round) {
            int idx = wb - 1 - t - 64 * round;
            int rv = (idx >= 0) ? ri[idx] : (r0 ^ 1);
            unsigned long long mm = __ballot(rv != r0);
            if (mm) {
                int lm = __ffsll((unsigned long long)mm) - 1; // lowest lane = largest idx
                h0 = wb - 64 * round - lm;                    // mismatch idx + 1
                break;
            }
        }
        float elv = 0.0f;
        if (t == 0) {                         // recompute C_head per frozen contract
            const float4* s4 = (const float4*)sdt;
            int gh = h0 >> 4, lh = h0 & 15;
            float4 q0 = s4[gh * 4 + 0], q1 = s4[gh * 4 + 1];
            float4 q2 = s4[gh * 4 + 2], q3 = s4[gh * 4 + 3];
            float vv[16] = { q0.x, q0.y, q0.z, q0.w, q1.x, q1.y, q1.z, q1.w,
                             q2.x, q2.y, q2.z, q2.w, q3.x, q3.y, q3.z, q3.w };
            float a2 = 0.0f, xl = 0.0f;
            #pragma unroll
            for (int j2 = 0; j2 < 16; ++j2) {
                if (j2 <= lh) { a2 = __fadd_rn(a2, vv[j2]); xl = vv[j2]; }
            }
            float Ch = a2;
            if (gh) {
                int j3 = gh - 1;
                float cj = (j3 >> 4) ? __fadd_rn(s1[j3], C2[(j3 >> 4) - 1]) : s1[j3];
                Ch = __fadd_rn(a2, cj);
            }
            elv = __fsub_rn(Ch, xl);
        }
        el_lead = __int_as_float(__builtin_amdgcn_readfirstlane(__float_as_int(elv)));
    }

    // ---- el via shfl from head lane (head lane's excl == el)
    int h = bits_le ? (63 - __clzll((long long)bits_le)) : 0;
    int esrc = bits_le ? h : t;
    float elh = __shfl(excl, esrc, 64);       // all lanes participate
    float el = bits_le ? elh : el_lead;

    // ---- weights
    float w = 0.0f, hr = 0.0f, hg = 0.0f, hb = 0.0f;
    if (valid) {
        float expo  = __fsub_rn(excl, el);
        float trans = __expf(-expo);
        float alpha = __fsub_rn(1.0f, __expf(-x));
        w  = __fmul_rn(trans, alpha);
        hr = hdr[3 * i + 0]; hg = hdr[3 * i + 1]; hb = hdr[3 * i + 2];
    }

    // ---- unsegmented inclusive wave scan (DPP, VALU pipe)
    float4 sc;
    sc.x = wscan(w);
    sc.y = wscan(__fmul_rn(w, hr));
    sc.z = wscan(__fmul_rn(w, hg));
    sc.w = wscan(__fmul_rn(w, hb));

    // ---- run base = scan value just before my run's first in-wave lane
    int bsrc = (h > 0) ? (h - 1) : t;
    float4 bs;
    bs.x = __shfl(sc.x, bsrc, 64);
    bs.y = __shfl(sc.y, bsrc, 64);
    bs.z = __shfl(sc.z, bsrc, 64);
    bs.w = __shfl(sc.w, bsrc, 64);
    if (h == 0) { bs.x = 0.f; bs.y = 0.f; bs.z = 0.f; bs.w = 0.f; }

    // ---- tails: one atomic partial-sum per (wave, run) piece
    bool nf = (t < 63) ? (((mask >> (t + 1)) & 1ull) != 0ull) : true;
    if (valid && nf && r >= 0) {
        float* o = out + 4 * r;
        atomicAdd(o + 0, sc.x - bs.x);
        atomicAdd(o + 1, sc.y - bs.y);
        atomicAdd(o + 2, sc.z - bs.z);
        atomicAdd(o + 3, sc.w - bs.w);
    }
}

extern "C" void kernel_launch(void* const* d_in, const int* in_sizes, int n_in,
                              void* d_out, int out_size, void* d_ws, size_t ws_size,
                              hipStream_t stream) {
    const float* ts  = (const float*)d_in[0];
    const float* te  = (const float*)d_in[1];
    const float* sg  = (const float*)d_in[2];
    const float* hdr = (const float*)d_in[3];
    const int*   ri  = (const int*)d_in[4];
    const int S      = in_sizes[0];          // 4194304 = 2^22
    const int n_rays = out_size / 4;
    const int N1 = S >> 4;                   // 262144
    const int N2 = N1 >> 4;                  // 16384

    char* w = (char*)d_ws;
    auto alloc = [&](size_t bytes) { char* p = w; w += (bytes + 255) & ~255ULL; return p; };
    float* sdt = (float*)alloc((size_t)S * 4);
    float* s1  = (float*)alloc((size_t)N1 * 4);
    float* T1  = (float*)alloc((size_t)N2 * 4);
    float* C2  = (float*)alloc((size_t)N2 * 4);

    k_bottom<<<dim3(N1 / TPB), dim3(TPB), 0, stream>>>(ts, te, sg, S, sdt, s1, T1,
                                                       (float4*)d_out, n_rays);
    k_mid   <<<dim3(1), dim3(1024), 0, stream>>>(T1, C2);
    k_render<<<dim3((S + TPB - 1) / TPB), dim3(TPB), 0, stream>>>(ri, sdt, s1, C2, hdr, S, (float*)d_out);
}

// Round 6
// 164.914 us; speedup vs baseline: 1.2916x; 1.0734x over previous
//
#include <hip/hip_runtime.h>

// NeRF render, numerics contract (frozen from r8, PASSED):
//   sdt_i = fmul(sg, fsub(te,ts));  blocked-16 XLA cumsum:
//   s1[g] = within-16 fold of T0 (T0[g] = fold16 of sdt);  upper recursion
//   16384->1024->64->4 sequential folds + combine adds -> C2[16384];
//   C1[j] = (j>>4)? fadd(s1[j], C2[(j>>4)-1]) : s1[j];
//   C_i = g? fadd(fold16_incl(i), C1[g-1]) : fold16_incl(i);
//   excl_i = fsub(C_i, sdt_i);  expo = fsub(excl_i, el[ray]);
//   w = fmul(exp(-expo), fsub(1, exp(-sdt_i))).
// r14: k_render -> 4 samples/thread. r5 post-mortem: k_render 50us at 16%
// HBM / 45% VALU / 70% occ = bound by ~250 VALU ops PER SAMPLE + serial
// cross-lane chains, not by any pipe. Now: group of 16 = 4 lanes; fold16 =
// in-thread serial 4-chain + 3 carry rounds (DPP row_shr:1), which
// reproduces the frozen left-fold chain EXACTLY (lane q continues from the
// true carry of lane q-1; leading fadd(0,x) is bit-exact for x>=+0).
// Head/el bookkeeping mostly in-thread; one int max-scan (associative) +
// 5 shfls for cross-lane el/bs. Segment sums: in-thread float4 prefix +
// wave scan of thread totals (atomics path, reorder-tolerant as before).
// el_lead probe + lane-0 C_head recompute: unchanged r5 code.
// k_bottom / k_mid: byte-identical to r5 (PASSED).

#define TPB 256
#define LDSF (256 * 17)      // padded tile: 256 groups x 16 + pad

// update_dpp with old=0: masked/invalid lanes yield exactly 0.0f.
#define DPP0(SRC, CTRL, RMASK, BC) __int_as_float(__builtin_amdgcn_update_dpp( \
        0, __float_as_int(SRC), (CTRL), (RMASK), 0xf, (BC)))

// int max with DPP-shifted operand (old=0 identity for keys >= 0)
#define IMAXD(V, CTRL, RMASK, BC) { \
    int _tmp = __builtin_amdgcn_update_dpp(0, (V), (CTRL), (RMASK), 0xf, (BC)); \
    (V) = ((V) > _tmp) ? (V) : _tmp; }

// serial left-fold prefix within each 16-lane row, exact contract order
// (used by k_bottom; leading fadd(acc,0) terms are bit-exact no-ops).
__device__ __forceinline__ float fold16_dpp(float x) {
    float a = 0.0f;
    a = __fadd_rn(a, DPP0(x, 0x110 | 15, 0xf, true));
    a = __fadd_rn(a, DPP0(x, 0x110 | 14, 0xf, true));
    a = __fadd_rn(a, DPP0(x, 0x110 | 13, 0xf, true));
    a = __fadd_rn(a, DPP0(x, 0x110 | 12, 0xf, true));
    a = __fadd_rn(a, DPP0(x, 0x110 | 11, 0xf, true));
    a = __fadd_rn(a, DPP0(x, 0x110 | 10, 0xf, true));
    a = __fadd_rn(a, DPP0(x, 0x110 |  9, 0xf, true));
    a = __fadd_rn(a, DPP0(x, 0x110 |  8, 0xf, true));
    a = __fadd_rn(a, DPP0(x, 0x110 |  7, 0xf, true));
    a = __fadd_rn(a, DPP0(x, 0x110 |  6, 0xf, true));
    a = __fadd_rn(a, DPP0(x, 0x110 |  5, 0xf, true));
    a = __fadd_rn(a, DPP0(x, 0x110 |  4, 0xf, true));
    a = __fadd_rn(a, DPP0(x, 0x110 |  3, 0xf, true));
    a = __fadd_rn(a, DPP0(x, 0x110 |  2, 0xf, true));
    a = __fadd_rn(a, DPP0(x, 0x110 |  1, 0xf, true));
    a = __fadd_rn(a, x);
    return a;
}

// inclusive 64-lane scan (segment sums only; rounding-free path)
__device__ __forceinline__ float wscan(float v) {
    v = __fadd_rn(v, DPP0(v, 0x111, 0xf, true));   // row_shr:1
    v = __fadd_rn(v, DPP0(v, 0x112, 0xf, true));   // row_shr:2
    v = __fadd_rn(v, DPP0(v, 0x114, 0xf, true));   // row_shr:4
    v = __fadd_rn(v, DPP0(v, 0x118, 0xf, true));   // row_shr:8
    v = __fadd_rn(v, DPP0(v, 0x142, 0xa, false));  // row_bcast15 -> rows 1,3
    v = __fadd_rn(v, DPP0(v, 0x143, 0xc, false));  // row_bcast31 -> rows 2,3
    return v;
}

__device__ __forceinline__ float sdt_c(float tsv, float tev, float sgv) {
    return __fmul_rn(sgv, __fsub_rn(tev, tsv));
}

// block = one 4096-float tile: coalesced loads, sdt written coalesced,
// staged into padded LDS; thread t serially folds its 16-group from LDS.
__global__ void k_bottom(const float* __restrict__ ts, const float* __restrict__ te,
                         const float* __restrict__ sg, int S,
                         float* __restrict__ sdt, float* __restrict__ s1,
                         float* __restrict__ T1,
                         float4* __restrict__ out4, int n_rays) {
    __shared__ float lds[LDSF];
    int t = threadIdx.x;
    int tile = blockIdx.x;                    // grid = N1/TPB = 1024 tiles
    int gid = tile * TPB + t;
    if (gid < n_rays) out4[gid] = make_float4(0.f, 0.f, 0.f, 0.f);
    const float4* ts4 = (const float4*)ts;
    const float4* te4 = (const float4*)te;
    const float4* sg4 = (const float4*)sg;
    float4* sdt4 = (float4*)sdt;
    #pragma unroll
    for (int k = 0; k < 4; ++k) {
        int idx4 = tile * 1024 + k * 256 + t;  // lane-contiguous float4
        float4 a = ts4[idx4], b = te4[idx4], c = sg4[idx4];
        float4 xo;
        xo.x = sdt_c(a.x, b.x, c.x);
        xo.y = sdt_c(a.y, b.y, c.y);
        xo.z = sdt_c(a.z, b.z, c.z);
        xo.w = sdt_c(a.w, b.w, c.w);
        sdt4[idx4] = xo;                       // coalesced write
        int fl = (k * 256 + t) << 2;           // float idx within tile
        int g0 = fl >> 4, j0 = fl & 15;
        float* p = &lds[g0 * 17 + j0];
        p[0] = xo.x; p[1] = xo.y; p[2] = xo.z; p[3] = xo.w;
    }
    __syncthreads();
    float acc = 0.0f;
    #pragma unroll
    for (int j = 0; j < 16; ++j) acc = __fadd_rn(acc, lds[t * 17 + j]);
    float acc2 = fold16_dpp(acc);              // within-16 row fold -> s1
    int g = tile * 256 + t;
    s1[g] = acc2;
    if ((t & 15) == 15) T1[g >> 4] = acc2;
}

// single block, 1024 threads: scan T1[16384] through levels 2..base -> C2.
__global__ void k_mid(const float* __restrict__ T1, float* __restrict__ C2) {
    __shared__ float T2sh[1024];
    __shared__ float s3sh[1024];   // becomes C3 in place
    __shared__ float s4sh[64];     // becomes C4 in place
    __shared__ float T3sh[64];
    __shared__ float T4sh[4];
    __shared__ float C5sh[4];
    int t = threadIdx.x;
    const float4* T14 = (const float4*)T1;
    float s2l[16];
    float acc = 0.0f;
    #pragma unroll
    for (int k = 0; k < 4; ++k) {
        float4 v = T14[t * 4 + k];
        acc = __fadd_rn(acc, v.x); s2l[k * 4 + 0] = acc;
        acc = __fadd_rn(acc, v.y); s2l[k * 4 + 1] = acc;
        acc = __fadd_rn(acc, v.z); s2l[k * 4 + 2] = acc;
        acc = __fadd_rn(acc, v.w); s2l[k * 4 + 3] = acc;
    }
    T2sh[t] = acc;
    __syncthreads();
    if (t < 64) {                  // level 3
        float a3 = 0.0f;
        for (int j = 0; j < 16; ++j) { a3 = __fadd_rn(a3, T2sh[t * 16 + j]); s3sh[t * 16 + j] = a3; }
        T3sh[t] = a3;
    }
    __syncthreads();
    if (t < 4) {                   // level 4
        float a4 = 0.0f;
        for (int j = 0; j < 16; ++j) { a4 = __fadd_rn(a4, T3sh[t * 16 + j]); s4sh[t * 16 + j] = a4; }
        T4sh[t] = a4;
    }
    __syncthreads();
    if (t == 0) {                  // base fold of 4
        float c = 0.0f;
        for (int r = 0; r < 4; ++r) { c = __fadd_rn(c, T4sh[r]); C5sh[r] = c; }
    }
    __syncthreads();
    if (t < 64) {                  // C4 in place
        int r = t >> 4;
        float v4 = s4sh[t];
        s4sh[t] = r ? __fadd_rn(v4, C5sh[r - 1]) : v4;
    }
    __syncthreads();
    {                              // C3 in place
        int r = t >> 4;
        float v3 = s3sh[t];
        float c3 = r ? __fadd_rn(v3, s4sh[r - 1]) : v3;
        s3sh[t] = c3;
    }
    __syncthreads();
    float c3m = t ? s3sh[t - 1] : 0.0f;   // C3[t-1]
    float4* C24 = (float4*)C2;
    #pragma unroll
    for (int k = 0; k < 4; ++k) {
        float4 o;
        o.x = t ? __fadd_rn(s2l[k * 4 + 0], c3m) : s2l[k * 4 + 0];
        o.y = t ? __fadd_rn(s2l[k * 4 + 1], c3m) : s2l[k * 4 + 1];
        o.z = t ? __fadd_rn(s2l[k * 4 + 2], c3m) : s2l[k * 4 + 2];
        o.w = t ? __fadd_rn(s2l[k * 4 + 3], c3m) : s2l[k * 4 + 3];
        C24[t * 4 + k] = o;
    }
}

// wave-autonomous render, 4 samples/thread (wave = 256 samples).
__global__ void k_render(const int* __restrict__ ri, const float* __restrict__ sdt,
                         const float* __restrict__ s1, const float* __restrict__ C2,
                         const float* __restrict__ hdr,
                         int S, float* __restrict__ out) {
    const int tid = blockIdx.x * TPB + threadIdx.x;
    const int t = threadIdx.x & 63;           // lane
    const int i0 = tid * 4;                   // first sample of this thread
    const bool valid = i0 < S;                // grid fits S exactly; guard anyway

    // ---- vector loads
    float4 xq = valid ? ((const float4*)sdt)[tid] : make_float4(0.f, 0.f, 0.f, 0.f);
    int4 rq;
    if (valid) rq = ((const int4*)ri)[tid];
    else { rq.x = rq.y = rq.z = rq.w = -1 - t; }

    // ---- previous-sample ray id (DPP from lane-1's rq.w; row-boundary
    // lanes (t%16==0) load ri[i0-1] from global, L1/L2-hot)
    int dpr = __builtin_amdgcn_update_dpp(0, rq.w, 0x111, 0xf, 0xf, true);
    int prev_r = dpr;
    if ((t & 15) == 0) prev_r = (i0 == 0 || !valid) ? (rq.x ^ 1) : ri[i0 - 1];

    bool f0 = prev_r != rq.x;
    bool f1 = rq.y != rq.x;
    bool f2 = rq.z != rq.y;
    bool f3 = rq.w != rq.z;
    unsigned long long mask0 = __ballot(f0);

    // ---- fold16 (exact contract chain): group = 4 lanes, q = t&3.
    // Lane q continues serially from the true carry of lane q-1.
    int q = t & 3;
    float p0 = __fadd_rn(0.0f, xq.x);
    float p1 = __fadd_rn(p0, xq.y);
    float p2 = __fadd_rn(p1, xq.z);
    float p3 = __fadd_rn(p2, xq.w);
    float pf = p3;                            // final acc (valid for q==0)
    #pragma unroll
    for (int rr = 1; rr <= 3; ++rr) {
        float cin = DPP0(pf, 0x111, 0xf, true);    // lane-1's pf
        float n0 = __fadd_rn(cin, xq.x);
        float n1 = __fadd_rn(n0, xq.y);
        float n2 = __fadd_rn(n1, xq.z);
        float n3 = __fadd_rn(n2, xq.w);
        bool me = (q == rr);
        p0 = me ? n0 : p0;
        p1 = me ? n1 : p1;
        p2 = me ? n2 : p2;
        p3 = me ? n3 : p3;
        pf = me ? n3 : pf;
    }

    // ---- upper-recursion carry (all 4 samples share group g)
    int g = i0 >> 4;
    float cj = 0.0f;
    if (valid && g) {
        int j3 = g - 1;
        cj = (j3 >> 4) ? __fadd_rn(s1[j3], C2[(j3 >> 4) - 1]) : s1[j3];
    }
    float C0 = g ? __fadd_rn(p0, cj) : p0;
    float C1v = g ? __fadd_rn(p1, cj) : p1;
    float C2v = g ? __fadd_rn(p2, cj) : p2;
    float C3v = g ? __fadd_rn(p3, cj) : p3;
    float e0 = __fsub_rn(C0, xq.x);
    float e1 = __fsub_rn(C1v, xq.y);
    float e2 = __fsub_rn(C2v, xq.z);
    float e3 = __fsub_rn(C3v, xq.w);

    // ---- el for the wave-leading run (head in an earlier wave)
    float el_lead = 0.0f;
    if (!(mask0 & 1ull)) {                    // wave-uniform branch
        int wbs = (tid - t) * 4;              // wave's first sample
        int r0v = __builtin_amdgcn_readfirstlane(rq.x);
        int h0 = 0;
        for (int round = 0; round < 65536; ++round) {
            int idx = wbs - 1 - t - 64 * round;
            int rv = (idx >= 0) ? ri[idx] : (r0v ^ 1);
            unsigned long long mm = __ballot(rv != r0v);
            if (mm) {
                int lm = __ffsll((unsigned long long)mm) - 1;
                h0 = wbs - 64 * round - lm;
                break;
            }
        }
        float elv = 0.0f;
        if (t == 0) {                         // recompute C_head, frozen fold
            const float4* s4 = (const float4*)sdt;
            int gh = h0 >> 4, lh = h0 & 15;
            float4 q0 = s4[gh * 4 + 0], q1 = s4[gh * 4 + 1];
            float4 q2 = s4[gh * 4 + 2], q3 = s4[gh * 4 + 3];
            float vv[16] = { q0.x, q0.y, q0.z, q0.w, q1.x, q1.y, q1.z, q1.w,
                             q2.x, q2.y, q2.z, q2.w, q3.x, q3.y, q3.z, q3.w };
            float a2 = 0.0f, xl = 0.0f;
            #pragma unroll
            for (int j2 = 0; j2 < 16; ++j2) {
                if (j2 <= lh) { a2 = __fadd_rn(a2, vv[j2]); xl = vv[j2]; }
            }
            float Ch = a2;
            if (gh) {
                int j3b = gh - 1;
                float cjb = (j3b >> 4) ? __fadd_rn(s1[j3b], C2[(j3b >> 4) - 1]) : s1[j3b];
                Ch = __fadd_rn(a2, cjb);
            }
            elv = __fsub_rn(Ch, xl);
        }
        el_lead = __int_as_float(__builtin_amdgcn_readfirstlane(__float_as_int(elv)));
    }

    // ---- per-sample last-head index within thread (-1 if none)
    int lh0 = f0 ? 0 : -1;
    int lh1 = f1 ? 1 : lh0;
    int lh2 = f2 ? 2 : lh1;
    int lh3 = f3 ? 3 : lh2;

    // ---- cross-lane source: last head lane strictly before me
    int key = (lh3 >= 0) ? (t + 1) : 0;
    int sk = __shfl_up(key, 1, 64);
    if (t == 0) sk = 0;
    int M = sk;                                // inclusive max-scan (assoc.)
    IMAXD(M, 0x111, 0xf, true)
    IMAXD(M, 0x112, 0xf, true)
    IMAXD(M, 0x114, 0xf, true)
    IMAXD(M, 0x118, 0xf, true)
    IMAXD(M, 0x142, 0xa, false)
    IMAXD(M, 0x143, 0xc, false)
    int src = M;                               // (head lane < me)+1, or 0
    int psrc = (src > 0) ? (src - 1) : t;

    // el at my last head (valid iff lh3>=0)
    float el_last = (lh3 == 3) ? e3 : (lh3 == 2) ? e2 : (lh3 == 1) ? e1 : e0;
    float rel = __shfl(el_last, psrc, 64);
    float el_prev = (src > 0) ? rel : el_lead;

    float el0 = (lh0 >= 0) ? e0 : el_prev;
    float el1 = (lh1 == 1) ? e1 : ((lh1 == 0) ? e0 : el_prev);
    float el2 = (lh2 == 2) ? e2 : ((lh2 == 1) ? e1 : ((lh2 == 0) ? e0 : el_prev));
    float el3 = (lh3 == 3) ? e3 : ((lh3 == 2) ? e2 : ((lh3 == 1) ? e1 :
                ((lh3 == 0) ? e0 : el_prev)));

    // ---- weights (frozen arithmetic)
    float4 h0v, h1v, h2v;
    if (valid) {
        const float4* h4 = (const float4*)hdr;
        h0v = h4[3 * tid + 0]; h1v = h4[3 * tid + 1]; h2v = h4[3 * tid + 2];
    } else {
        h0v = h1v = h2v = make_float4(0.f, 0.f, 0.f, 0.f);
    }
    float w0 = 0.f, w1 = 0.f, w2 = 0.f, w3 = 0.f;
    if (valid) {
        w0 = __fmul_rn(__expf(-__fsub_rn(e0, el0)), __fsub_rn(1.0f, __expf(-xq.x)));
        w1 = __fmul_rn(__expf(-__fsub_rn(e1, el1)), __fsub_rn(1.0f, __expf(-xq.y)));
        w2 = __fmul_rn(__expf(-__fsub_rn(e2, el2)), __fsub_rn(1.0f, __expf(-xq.z)));
        w3 = __fmul_rn(__expf(-__fsub_rn(e3, el3)), __fsub_rn(1.0f, __expf(-xq.w)));
    }
    // per-sample contribution vectors (w, w*r, w*g, w*b)
    float4 v0 = make_float4(w0, __fmul_rn(w0, h0v.x), __fmul_rn(w0, h0v.y), __fmul_rn(w0, h0v.z));
    float4 v1 = make_float4(w1, __fmul_rn(w1, h0v.w), __fmul_rn(w1, h1v.x), __fmul_rn(w1, h1v.y));
    float4 v2 = make_float4(w2, __fmul_rn(w2, h1v.z), __fmul_rn(w2, h1v.w), __fmul_rn(w2, h2v.x));
    float4 v3 = make_float4(w3, __fmul_rn(w3, h2v.y), __fmul_rn(w3, h2v.z), __fmul_rn(w3, h2v.w));

    // ---- in-thread inclusive prefix of v
    float4 V0 = v0;
    float4 V1 = make_float4(V0.x + v1.x, V0.y + v1.y, V0.z + v1.z, V0.w + v1.w);
    float4 V2 = make_float4(V1.x + v2.x, V1.y + v2.y, V1.z + v2.z, V1.w + v2.w);
    float4 V3 = make_float4(V2.x + v3.x, V2.y + v3.y, V2.z + v3.z, V2.w + v3.w);

    // ---- wave scan of thread totals -> exclusive base E
    float4 W;
    W.x = wscan(V3.x); W.y = wscan(V3.y); W.z = wscan(V3.z); W.w = wscan(V3.w);
    float4 E;
    E.x = __shfl_up(W.x, 1, 64);
    E.y = __shfl_up(W.y, 1, 64);
    E.z = __shfl_up(W.z, 1, 64);
    E.w = __shfl_up(W.w, 1, 64);
    if (t == 0) { E.x = 0.f; E.y = 0.f; E.z = 0.f; E.w = 0.f; }

    // ---- base (prefix before run head) at my last head; shfl for cross-lane
    float4 Vm1 = (lh3 == 1) ? V0 : ((lh3 == 2) ? V1 : V2);   // V_{lh3-1}
    float4 bs_last;
    if (lh3 > 0) {
        bs_last = make_float4(E.x + Vm1.x, E.y + Vm1.y, E.z + Vm1.z, E.w + Vm1.w);
    } else {
        bs_last = E;                           // head at sample 0 (or unused)
    }
    float4 rbs;
    rbs.x = __shfl(bs_last.x, psrc, 64);
    rbs.y = __shfl(bs_last.y, psrc, 64);
    rbs.z = __shfl(bs_last.z, psrc, 64);
    rbs.w = __shfl(bs_last.w, psrc, 64);
    float4 bs_prev = (src > 0) ? rbs : make_float4(0.f, 0.f, 0.f, 0.f);

    // ---- tails: emit one atomic piece per (wave, run) segment end
    bool t0 = f1, t1 = f2, t2 = f3;
    bool t3 = (t < 63) ? (((mask0 >> (t + 1)) & 1ull) != 0ull) : true;

    if (valid) {
        #pragma unroll
        for (int j = 0; j < 4; ++j) {
            bool tl = (j == 0) ? t0 : (j == 1) ? t1 : (j == 2) ? t2 : t3;
            if (!tl) continue;
            int lhj = (j == 0) ? lh0 : (j == 1) ? lh1 : (j == 2) ? lh2 : lh3;
            float4 Vj = (j == 0) ? V0 : (j == 1) ? V1 : (j == 2) ? V2 : V3;
            int rj = (j == 0) ? rq.x : (j == 1) ? rq.y : (j == 2) ? rq.z : rq.w;
            float4 bsj;
            if (lhj >= 0) {
                if (lhj > 0) {
                    float4 Vh = (lhj == 1) ? V0 : ((lhj == 2) ? V1 : V2);
                    bsj = make_float4(E.x + Vh.x, E.y + Vh.y, E.z + Vh.z, E.w + Vh.w);
                } else {
                    bsj = E;
                }
            } else {
                bsj = bs_prev;
            }
            float px = (E.x + Vj.x) - bsj.x;
            float py = (E.y + Vj.y) - bsj.y;
            float pz = (E.z + Vj.z) - bsj.z;
            float pw = (E.w + Vj.w) - bsj.w;
            if (rj >= 0) {
                float* o = out + 4 * rj;
                atomicAdd(o + 0, px);
                atomicAdd(o + 1, py);
                atomicAdd(o + 2, pz);
                atomicAdd(o + 3, pw);
            }
        }
    }
}

extern "C" void kernel_launch(void* const* d_in, const int* in_sizes, int n_in,
                              void* d_out, int out_size, void* d_ws, size_t ws_size,
                              hipStream_t stream) {
    const float* ts  = (const float*)d_in[0];
    const float* te  = (const float*)d_in[1];
    const float* sg  = (const float*)d_in[2];
    const float* hdr = (const float*)d_in[3];
    const int*   ri  = (const int*)d_in[4];
    const int S      = in_sizes[0];          // 4194304 = 2^22
    const int n_rays = out_size / 4;
    const int N1 = S >> 4;                   // 262144
    const int N2 = N1 >> 4;                  // 16384

    char* w = (char*)d_ws;
    auto alloc = [&](size_t bytes) { char* p = w; w += (bytes + 255) & ~255ULL; return p; };
    float* sdt = (float*)alloc((size_t)S * 4);
    float* s1  = (float*)alloc((size_t)N1 * 4);
    float* T1  = (float*)alloc((size_t)N2 * 4);
    float* C2  = (float*)alloc((size_t)N2 * 4);

    k_bottom<<<dim3(N1 / TPB), dim3(TPB), 0, stream>>>(ts, te, sg, S, sdt, s1, T1,
                                                       (float4*)d_out, n_rays);
    k_mid   <<<dim3(1), dim3(1024), 0, stream>>>(T1, C2);
    k_render<<<dim3(S / (TPB * 4)), dim3(TPB), 0, stream>>>(ri, sdt, s1, C2, hdr, S, (float*)d_out);
}